// Round 3
// baseline (415.090 us; speedup 1.0000x reference)
//
#include <hip/hip_runtime.h>

// ---------------------------------------------------------------------------
// HypER pipeline on MI355X. B=8192, D=400, OC=32, FW=9, J=392, R=288,
// FCLEN=12544.
//   M    = W_E @ fc1_w.T            (400x288)      prep_M
//   head = bf16(UE[ht0]) @ bf16(W_E)               gemm_s1<80>  (T14 pipeline)
//   k    = bf16(UE[ht1]) @ bf16(M) + fc1_b         gemm_s1<96>
//   bn0 -> a0,b0 scalars                           bn0_part/bn0_fin
//   conv[b,o,j] -> bf16 convb + per-ch stats       conv_k (reg sliding window)
//   bn1 -> alpha,beta; fold into fc_w              bn1_fin, prep_fcw
//   pre  = convb @ Bprep^T  (split-K=4, MFMA,      fc_gemm_sk (3-buf counted
//          global_load_lds + XOR swizzle)           vmcnt pipeline + setprio)
//   reduce partials + bias + bn2 partial stats     reduce_bn2
//   bn2 finalize + relu                            bn2_fin, final_k
// ---------------------------------------------------------------------------

#define BB   8192
#define DD   400
#define RR   288
#define OCC  32
#define FWW  9
#define JJ   392
#define FCLEN 12544
#define KSPL 4
#define KS   (FCLEN / KSPL)   /* 3136 */
#define KSTEPS (KS / 64)      /* 49 */
#define EPSF 1e-5

typedef __attribute__((ext_vector_type(8))) short bf16x8;
typedef __attribute__((ext_vector_type(4))) float f32x4;

__device__ inline unsigned short f2bf(float f) {
    union { float f; unsigned u; } x; x.f = f;
    unsigned r = x.u + 0x7fffu + ((x.u >> 16) & 1u);
    return (unsigned short)(r >> 16);
}

__device__ inline void gload16(const void* g, void* l) {
    __builtin_amdgcn_global_load_lds((const __attribute__((address_space(1))) unsigned int*)g,
                                     (__attribute__((address_space(3))) unsigned int*)l, 16, 0, 0);
}

__device__ inline float block_reduce_256(float v, float* red) {
    #pragma unroll
    for (int m = 1; m < 64; m <<= 1) v += __shfl_xor(v, m);
    int wv = threadIdx.x >> 6;
    if ((threadIdx.x & 63) == 0) red[wv] = v;
    __syncthreads();
    float r = 0.f;
    if (threadIdx.x == 0) r = red[0] + red[1] + red[2] + red[3];
    return r;
}

// ---------------- prep_M: M[i][r] = sum_d W_E[i][d]*fc1_w[r][d] ------------
__global__ __launch_bounds__(256) void prep_M(const float* __restrict__ WE,
                                              const float* __restrict__ f1w,
                                              float* __restrict__ Mout) {
    __shared__ float sA[16][17];
    __shared__ float sB[16][17];
    int tx = threadIdx.x, ty = threadIdx.y;
    int r0 = blockIdx.x * 16, i0 = blockIdx.y * 16;
    float acc = 0.f;
    for (int d0 = 0; d0 < DD; d0 += 16) {
        sA[ty][tx] = WE[(size_t)(i0 + ty) * DD + d0 + tx];
        sB[ty][tx] = f1w[(size_t)(r0 + ty) * DD + d0 + tx];
        __syncthreads();
        #pragma unroll
        for (int dd = 0; dd < 16; ++dd) acc = fmaf(sA[ty][dd], sB[tx][dd], acc);
        __syncthreads();
    }
    Mout[(size_t)(i0 + ty) * RR + r0 + tx] = acc;
}

// ------------- stage-1 gathered GEMM, T14 async-stage pipeline -------------
template <int BN>
__global__ __launch_bounds__(256) void gemm_s1(const float* __restrict__ A,
                                               const int* __restrict__ idx,
                                               const float* __restrict__ Bm,
                                               const float* __restrict__ bias,
                                               float* __restrict__ C, int N) {
    constexpr int BNF = BN / 16;
    constexpr int BCH = 64 * (BN / 4) / 256;   // B float4-chunks per thread
    __shared__ unsigned short Al[64][72];
    __shared__ unsigned short Bl[BN][72];
    __shared__ int ridx[64];
    int tid = threadIdx.x;
    int bm = blockIdx.x, bn = blockIdx.y;
    if (tid < 64) ridx[tid] = idx[bm * 64 + tid];
    int lane = tid & 63, wv = tid >> 6;
    int m16 = lane & 15, kb = lane >> 4;
    f32x4 acc[BNF];
    #pragma unroll
    for (int nb = 0; nb < BNF; ++nb) acc[nb] = (f32x4){0.f, 0.f, 0.f, 0.f};
    __syncthreads();

    float4 av[4];
    float4 bv[BCH];
    auto LOADR = [&](int k0) {
        #pragma unroll
        for (int r = 0; r < 4; ++r) {
            int c = tid + 256 * r;
            int row = c >> 4, kq = c & 15;
            int gk = k0 + kq * 4;
            av[r] = (float4){0.f, 0.f, 0.f, 0.f};
            if (gk < DD) av[r] = *(const float4*)(A + (size_t)ridx[row] * DD + gk);
        }
        #pragma unroll
        for (int r = 0; r < BCH; ++r) {
            int c = tid + 256 * r;
            int kk2 = c / (BN / 4), nq = c % (BN / 4);
            int gk = k0 + kk2;
            bv[r] = (float4){0.f, 0.f, 0.f, 0.f};
            if (gk < DD) bv[r] = *(const float4*)(Bm + (size_t)gk * N + bn * BN + nq * 4);
        }
    };
    auto WRITELDS = [&]() {
        #pragma unroll
        for (int r = 0; r < 4; ++r) {
            int c = tid + 256 * r;
            int row = c >> 4, kq = c & 15;
            ushort4 p;
            p.x = f2bf(av[r].x); p.y = f2bf(av[r].y); p.z = f2bf(av[r].z); p.w = f2bf(av[r].w);
            *(ushort4*)&Al[row][kq * 4] = p;
        }
        #pragma unroll
        for (int r = 0; r < BCH; ++r) {
            int c = tid + 256 * r;
            int kk2 = c / (BN / 4), nq = c % (BN / 4);
            Bl[nq * 4 + 0][kk2] = f2bf(bv[r].x);
            Bl[nq * 4 + 1][kk2] = f2bf(bv[r].y);
            Bl[nq * 4 + 2][kk2] = f2bf(bv[r].z);
            Bl[nq * 4 + 3][kk2] = f2bf(bv[r].w);
        }
    };

    LOADR(0);
    for (int kt = 0; kt < 7; ++kt) {
        WRITELDS();
        __syncthreads();
        if (kt + 1 < 7) LOADR((kt + 1) * 64);   // latency hides under MFMA
        #pragma unroll
        for (int ks = 0; ks < 2; ++ks) {
            bf16x8 a = *(const bf16x8*)&Al[wv * 16 + m16][ks * 32 + kb * 8];
            #pragma unroll
            for (int nb = 0; nb < BNF; ++nb) {
                bf16x8 b = *(const bf16x8*)&Bl[nb * 16 + m16][ks * 32 + kb * 8];
                acc[nb] = __builtin_amdgcn_mfma_f32_16x16x32_bf16(a, b, acc[nb], 0, 0, 0);
            }
        }
        __syncthreads();
    }
    #pragma unroll
    for (int nb = 0; nb < BNF; ++nb)
        #pragma unroll
        for (int rr = 0; rr < 4; ++rr) {
            int gr = bm * 64 + wv * 16 + kb * 4 + rr;
            int gc = bn * BN + nb * 16 + m16;
            float v = acc[nb][rr];
            if (bias) v += bias[gc];
            C[(size_t)gr * N + gc] = v;
        }
}

// ---------------- bn0 stats over head (scalar mean/var) --------------------
__global__ __launch_bounds__(256) void bn0_part(const float* __restrict__ head,
                                                float* __restrict__ part) {
    __shared__ float red[8];
    const size_t total4 = (size_t)BB * DD / 4;
    float s1 = 0.f, s2 = 0.f;
    for (size_t i = (size_t)blockIdx.x * 256 + threadIdx.x; i < total4; i += 256 * 256) {
        float4 v = ((const float4*)head)[i];
        s1 += v.x + v.y + v.z + v.w;
        s2 += v.x * v.x + v.y * v.y + v.z * v.z + v.w * v.w;
    }
    float t1 = block_reduce_256(s1, red);
    float t2 = block_reduce_256(s2, red + 4);
    if (threadIdx.x == 0) { part[blockIdx.x * 2] = t1; part[blockIdx.x * 2 + 1] = t2; }
}

__global__ __launch_bounds__(256) void bn0_fin(const float* __restrict__ part,
                                               const float* __restrict__ g,
                                               const float* __restrict__ b,
                                               float* __restrict__ ab0) {
    __shared__ float red[8];
    float s1 = part[threadIdx.x * 2], s2 = part[threadIdx.x * 2 + 1];
    float t1 = block_reduce_256(s1, red);
    float t2 = block_reduce_256(s2, red + 4);
    if (threadIdx.x == 0) {
        double n = (double)BB * DD;
        double mean = (double)t1 / n;
        double var = (double)t2 / n - mean * mean;
        float a0 = (float)((double)g[0] / sqrt(var + EPSF));
        float b0 = (float)((double)b[0] - mean * a0);
        ab0[0] = a0; ab0[1] = b0;
    }
}

// ------ per-sample conv: sliding window in regs, wave owns 8 channels ------
__global__ __launch_bounds__(256) void conv_k(const float* __restrict__ head,
                                              const float* __restrict__ kbuf,
                                              const float* __restrict__ ab0,
                                              unsigned short* __restrict__ convb,
                                              float* __restrict__ chpartT) {
    __shared__ float xs[DD];
    __shared__ float ks[RR];
    int b = blockIdx.x, tid = threadIdx.x;
    float a0 = ab0[0], b0 = ab0[1];
    for (int i = tid; i < DD; i += 256) xs[i] = fmaf(head[(size_t)b * DD + i], a0, b0);
    for (int i = tid; i < RR; i += 256) ks[i] = kbuf[(size_t)b * RR + i];
    __syncthreads();
    int lane = tid & 63, wv = tid >> 6;
    unsigned short* orow = convb + (size_t)b * FCLEN;
    float kk[8][FWW];
    #pragma unroll
    for (int oi = 0; oi < 8; ++oi)
        #pragma unroll
        for (int w2 = 0; w2 < FWW; ++w2) kk[oi][w2] = ks[(wv * 8 + oi) * FWW + w2];
    float s1[8], s2[8];
    #pragma unroll
    for (int oi = 0; oi < 8; ++oi) { s1[oi] = 0.f; s2[oi] = 0.f; }
    #pragma unroll
    for (int jt = 0; jt < 2; ++jt) {
        int j0 = jt * 256 + lane * 4;
        if (j0 < JJ) {
            const float4* x4 = (const float4*)xs;
            float4 va = x4[(j0 >> 2)], vb = x4[(j0 >> 2) + 1], vc = x4[(j0 >> 2) + 2];
            float x[12] = {va.x, va.y, va.z, va.w, vb.x, vb.y, vb.z, vb.w, vc.x, vc.y, vc.z, vc.w};
            #pragma unroll
            for (int oi = 0; oi < 8; ++oi) {
                float acc[4];
                #pragma unroll
                for (int q = 0; q < 4; ++q) {
                    float a = 0.f;
                    #pragma unroll
                    for (int w2 = 0; w2 < FWW; ++w2) a = fmaf(x[q + w2], kk[oi][w2], a);
                    acc[q] = a;
                }
                ushort4 p;
                p.x = f2bf(acc[0]); p.y = f2bf(acc[1]); p.z = f2bf(acc[2]); p.w = f2bf(acc[3]);
                *(ushort4*)(orow + (wv * 8 + oi) * JJ + j0) = p;
                #pragma unroll
                for (int q = 0; q < 4; ++q) { s1[oi] += acc[q]; s2[oi] = fmaf(acc[q], acc[q], s2[oi]); }
            }
        }
    }
    #pragma unroll
    for (int oi = 0; oi < 8; ++oi) {
        float a = s1[oi], c = s2[oi];
        #pragma unroll
        for (int m = 1; m < 64; m <<= 1) { a += __shfl_xor(a, m); c += __shfl_xor(c, m); }
        if (lane == 0) {
            int o = wv * 8 + oi;
            chpartT[(size_t)o * BB + b] = a;
            chpartT[(size_t)(OCC + o) * BB + b] = c;
        }
    }
}

__global__ __launch_bounds__(256) void bn1_fin(const float* __restrict__ chpartT,
                                               const float* __restrict__ g1,
                                               const float* __restrict__ b1,
                                               float* __restrict__ alphabeta) {
    __shared__ float red[8];
    int o = blockIdx.x, tid = threadIdx.x;
    float s1 = 0.f, s2 = 0.f;
    for (int t = tid; t < BB; t += 256) {
        s1 += chpartT[(size_t)o * BB + t];
        s2 += chpartT[(size_t)(OCC + o) * BB + t];
    }
    float t1 = block_reduce_256(s1, red);
    float t2 = block_reduce_256(s2, red + 4);
    if (tid == 0) {
        double n = (double)BB * JJ;
        double mean = (double)t1 / n;
        double var = (double)t2 / n - mean * mean;
        float al = (float)((double)g1[o] / sqrt(var + EPSF));
        float be = (float)((double)b1[o] - mean * al);
        alphabeta[o] = al; alphabeta[OCC + o] = be;
    }
}

// ------- fold bn1 into fc_w: Bprep = bf16(fc_w*alpha); bias2 ---------------
__global__ __launch_bounds__(256) void prep_fcw(const float* __restrict__ fc_w,
                                                const float* __restrict__ fc_b,
                                                const float* __restrict__ alphabeta,
                                                unsigned short* __restrict__ Bp,
                                                float* __restrict__ bias2) {
    __shared__ float al[OCC], be[OCC];
    __shared__ float red[8];
    int d = blockIdx.x, tid = threadIdx.x;
    if (tid < OCC) { al[tid] = alphabeta[tid]; be[tid] = alphabeta[OCC + tid]; }
    __syncthreads();
    const float* row = fc_w + (size_t)d * FCLEN;
    unsigned short* orow = Bp + (size_t)d * FCLEN;
    float bacc = 0.f;
    for (int o = 0; o < OCC; ++o) {
        float a = al[o], bb = be[o];
        for (int j = tid; j < JJ; j += 256) {
            float wv = row[o * JJ + j];
            orow[o * JJ + j] = f2bf(wv * a);
            bacc = fmaf(wv, bb, bacc);
        }
    }
    float t = block_reduce_256(bacc, red);
    if (tid == 0) bias2[d] = fc_b[d] + t;
}

// -------- big FC GEMM, split-K=4, 3-buffer counted-vmcnt pipeline ----------
// LDS linear dest; source pre-swizzled per-lane; ds_read applies same XOR.
// Steady state: stage(t+2) issued, compute(t), wait own t+1 loads (vmcnt=own
// t+2 count, never 0), barrier. T5 setprio around the MFMA cluster.
__global__ __launch_bounds__(256, 2) void fc_gemm_sk(const unsigned short* __restrict__ A,
                                                     const unsigned short* __restrict__ Bp,
                                                     float* __restrict__ P) {
    __shared__ unsigned short Al[3][128 * 64];   // 3 x 16 KiB
    __shared__ unsigned short Bl[3][80 * 64];    // 3 x 10 KiB
    int tid = threadIdx.x;
    int bm = blockIdx.x, bn = blockIdx.y, bz = blockIdx.z;
    int lane = tid & 63, wv = tid >> 6;
    int m16 = lane & 15, kb = lane >> 4;
    int srow = lane >> 3, scol = lane & 7;
    int sw = m16 & 7;
    f32x4 acc[2][5];
    #pragma unroll
    for (int mi = 0; mi < 2; ++mi)
        #pragma unroll
        for (int nb = 0; nb < 5; ++nb) acc[mi][nb] = (f32x4){0.f, 0.f, 0.f, 0.f};
    const unsigned short* Ab = A + (size_t)(bm * 128 + srow) * FCLEN + (size_t)bz * KS + ((scol ^ srow) << 3);
    const unsigned short* Bb = Bp + (size_t)(bn * 80 + srow) * FCLEN + (size_t)bz * KS + ((scol ^ srow) << 3);

    auto STAGE = [&](int t, int buf) {   // waves 0,1 issue 7 loads; 2,3 issue 6
        size_t koff = (size_t)t * 64;
        #pragma unroll
        for (int i = 0; i < 7; ++i) {
            int c = wv + i * 4;
            if (c < 16) gload16(Ab + (size_t)c * 8 * FCLEN + koff, &Al[buf][c * 512]);
            else if (c < 26) gload16(Bb + (size_t)(c - 16) * 8 * FCLEN + koff, &Bl[buf][(c - 16) * 512]);
        }
    };

    STAGE(0, 0);
    STAGE(1, 1);
    if (wv < 2) asm volatile("s_waitcnt vmcnt(7)" ::: "memory");
    else        asm volatile("s_waitcnt vmcnt(6)" ::: "memory");
    __builtin_amdgcn_s_barrier();
    __builtin_amdgcn_sched_barrier(0);

    int cur = 0;
    for (int t = 0; t < KSTEPS; ++t) {
        int nxt = cur + 2; if (nxt >= 3) nxt -= 3;
        bool do_stage = (t + 2) < KSTEPS;
        if (do_stage) STAGE(t + 2, nxt);
        const unsigned short* Ac = Al[cur];
        const unsigned short* Bc = Bl[cur];
        int rA0 = (wv * 32 + m16) * 64;
        int rA1 = rA0 + 16 * 64;
        __builtin_amdgcn_s_setprio(1);
        #pragma unroll
        for (int ks2 = 0; ks2 < 2; ++ks2) {
            int ch = (((ks2 * 4 + kb) ^ sw) << 3);
            bf16x8 a0 = *(const bf16x8*)(Ac + rA0 + ch);
            bf16x8 a1 = *(const bf16x8*)(Ac + rA1 + ch);
            #pragma unroll
            for (int nb = 0; nb < 5; ++nb) {
                bf16x8 b = *(const bf16x8*)(Bc + (nb * 16 + m16) * 64 + ch);
                acc[0][nb] = __builtin_amdgcn_mfma_f32_16x16x32_bf16(a0, b, acc[0][nb], 0, 0, 0);
                acc[1][nb] = __builtin_amdgcn_mfma_f32_16x16x32_bf16(a1, b, acc[1][nb], 0, 0, 0);
            }
        }
        __builtin_amdgcn_s_setprio(0);
        if (do_stage) {
            if (wv < 2) asm volatile("s_waitcnt vmcnt(7)" ::: "memory");
            else        asm volatile("s_waitcnt vmcnt(6)" ::: "memory");
        } else {
            asm volatile("s_waitcnt vmcnt(0)" ::: "memory");
        }
        __builtin_amdgcn_s_barrier();
        __builtin_amdgcn_sched_barrier(0);
        cur = cur + 1; if (cur >= 3) cur -= 3;
    }

    float* Po = P + (size_t)bz * BB * DD;
    #pragma unroll
    for (int mi = 0; mi < 2; ++mi)
        #pragma unroll
        for (int nb = 0; nb < 5; ++nb)
            #pragma unroll
            for (int rr = 0; rr < 4; ++rr) {
                int gr = bm * 128 + wv * 32 + mi * 16 + kb * 4 + rr;
                int gc = bn * 80 + nb * 16 + m16;
                Po[(size_t)gr * DD + gc] = acc[mi][nb][rr];
            }
}

// ------ reduce split-K partials + bias, emit bn2 per-column partials -------
__global__ __launch_bounds__(256) void reduce_bn2(const float* __restrict__ P,
                                                  const float* __restrict__ bias2,
                                                  float* __restrict__ out,
                                                  float* __restrict__ part) {
    int blk = blockIdx.x, tid = threadIdx.x;   // 128 blocks x 64 rows
    int r0 = blk * 64;
    const size_t S = (size_t)BB * DD;
    bool hasb = tid < DD - 256;
    float bia = bias2[tid];
    float bib = hasb ? bias2[256 + tid] : 0.f;
    float s1a = 0.f, s2a = 0.f, s1b = 0.f, s2b = 0.f;
    for (int r = 0; r < 64; ++r) {
        size_t base = (size_t)(r0 + r) * DD;
        float v = P[base + tid] + P[S + base + tid] + P[2 * S + base + tid] + P[3 * S + base + tid] + bia;
        out[base + tid] = v;
        s1a += v; s2a = fmaf(v, v, s2a);
        if (hasb) {
            size_t b2i = base + 256 + tid;
            float u = P[b2i] + P[S + b2i] + P[2 * S + b2i] + P[3 * S + b2i] + bib;
            out[b2i] = u;
            s1b += u; s2b = fmaf(u, u, s2b);
        }
    }
    float* p = part + (size_t)blk * (DD * 2);
    p[tid * 2] = s1a; p[tid * 2 + 1] = s2a;
    if (hasb) { p[(256 + tid) * 2] = s1b; p[(256 + tid) * 2 + 1] = s2b; }
}

__global__ __launch_bounds__(128) void bn2_fin(const float* __restrict__ part,
                                               const float* __restrict__ g2,
                                               const float* __restrict__ b2,
                                               float* __restrict__ sc,
                                               float* __restrict__ sh) {
    __shared__ float red[4];
    int col = blockIdx.x, tid = threadIdx.x;
    float s1 = part[(size_t)tid * (DD * 2) + col * 2];
    float s2 = part[(size_t)tid * (DD * 2) + col * 2 + 1];
    #pragma unroll
    for (int m = 1; m < 64; m <<= 1) { s1 += __shfl_xor(s1, m); s2 += __shfl_xor(s2, m); }
    int wv = tid >> 6;
    if ((tid & 63) == 0) { red[wv] = s1; red[2 + wv] = s2; }
    __syncthreads();
    if (tid == 0) {
        double t1 = (double)red[0] + red[1];
        double t2 = (double)red[2] + red[3];
        double mean = t1 / (double)BB;
        double var = t2 / (double)BB - mean * mean;
        float s = (float)((double)g2[col] / sqrt(var + EPSF));
        sc[col] = s;
        sh[col] = (float)((double)b2[col] - mean * s);
    }
}

__global__ __launch_bounds__(256) void final_k(float* __restrict__ out,
                                               const float* __restrict__ sc,
                                               const float* __restrict__ sh) {
    __shared__ float lsc[DD], lsh[DD];
    int tid = threadIdx.x;
    for (int c = tid; c < DD; c += 256) { lsc[c] = sc[c]; lsh[c] = sh[c]; }
    __syncthreads();
    size_t base = (size_t)blockIdx.x * 4 * DD;
    for (int r = 0; r < 4; ++r)
        for (int c = tid; c < DD; c += 256) {
            size_t i = base + (size_t)r * DD + c;
            float v = fmaf(out[i], lsc[c], lsh[c]);
            out[i] = v > 0.f ? v : 0.f;
        }
}

// ---------------------------------------------------------------------------
extern "C" void kernel_launch(void* const* d_in, const int* in_sizes, int n_in,
                              void* d_out, int out_size, void* d_ws, size_t ws_size,
                              hipStream_t stream) {
    const int* ht      = (const int*)d_in[0];
    const float* UE    = (const float*)d_in[1];
    const float* W_E   = (const float*)d_in[2];
    const float* fc1_w = (const float*)d_in[3];
    const float* fc1_b = (const float*)d_in[4];
    const float* fc_w  = (const float*)d_in[5];
    const float* fc_b  = (const float*)d_in[6];
    const float* bn0_g = (const float*)d_in[7];
    const float* bn0_b = (const float*)d_in[8];
    const float* bn1_g = (const float*)d_in[9];
    const float* bn1_b = (const float*)d_in[10];
    const float* bn2_g = (const float*)d_in[11];
    const float* bn2_b = (const float*)d_in[12];
    float* out = (float*)d_out;

    char* w = (char*)d_ws;
    unsigned short* convb = (unsigned short*)w; w += (size_t)BB * FCLEN * 2;      // 205.5 MB
    unsigned short* Bprep = (unsigned short*)w; w += (size_t)DD * FCLEN * 2;      // 10 MB
    float* chpartT = (float*)w; w += (size_t)2 * OCC * BB * 4;                    // 2.1 MB
    float* bn0p = (float*)w;  w += 256 * 2 * 4;
    float* ab0 = (float*)w;   w += 64;
    float* alphabeta = (float*)w; w += 64 * 4;
    float* bias2 = (float*)w; w += DD * 4;
    float* bn2p = (float*)w;  w += (size_t)128 * DD * 2 * 4;
    float* bn2sc = (float*)w; w += DD * 4;
    float* bn2sh = (float*)w; w += DD * 4;
    // split-K partial region (52.4 MB), aliased over head/kbuf/Mbuf (dead by
    // the time fc_gemm_sk runs):
    float* P = (float*)w;     w += (size_t)KSPL * BB * DD * 4;
    float* head = P;                      // 13.1 MB, consumed by conv_k/bn0
    float* kbuf = head + (size_t)BB * DD; // 9.4 MB, consumed by conv_k
    float* Mbuf = kbuf + (size_t)BB * RR; // 0.46 MB, consumed by gemm_s1<96>
    (void)ws_size; (void)in_sizes; (void)n_in; (void)out_size;

    prep_M<<<dim3(RR / 16, DD / 16), dim3(16, 16), 0, stream>>>(W_E, fc1_w, Mbuf);
    gemm_s1<80><<<dim3(BB / 64, DD / 80), 256, 0, stream>>>(UE, ht, W_E, nullptr, head, DD);
    gemm_s1<96><<<dim3(BB / 64, RR / 96), 256, 0, stream>>>(UE, ht + BB, Mbuf, fc1_b, kbuf, RR);
    bn0_part<<<256, 256, 0, stream>>>(head, bn0p);
    bn0_fin<<<1, 256, 0, stream>>>(bn0p, bn0_g, bn0_b, ab0);
    conv_k<<<BB, 256, 0, stream>>>(head, kbuf, ab0, convb, chpartT);
    bn1_fin<<<OCC, 256, 0, stream>>>(chpartT, bn1_g, bn1_b, alphabeta);
    prep_fcw<<<DD, 256, 0, stream>>>(fc_w, fc_b, alphabeta, Bprep, bias2);
    fc_gemm_sk<<<dim3(BB / 128, DD / 80, KSPL), 256, 0, stream>>>(convb, Bprep, P);
    reduce_bn2<<<128, 256, 0, stream>>>(P, bias2, out, bn2p);
    bn2_fin<<<DD, 128, 0, stream>>>(bn2p, bn2_g, bn2_b, bn2sc, bn2sh);
    final_k<<<2048, 256, 0, stream>>>(out, bn2sc, bn2sh);
}